// Round 3
// baseline (94.648 us; speedup 1.0000x reference)
//
#include <hip/hip_runtime.h>
#include <math.h>

// QuantumLSTMClassifier — analytic collapse, single fused kernel.
//
// Identity chain: H|0> = |+> is an X eigenstate, so RX(q_in) is a global
// phase; the CNOT ring is a basis permutation; PauliZ expvals of the product
// state factorize. Hence q_feat depends only on qw:
//   z_j       = -sin(qw[g,0,j])
//   feat[g,0] = prod_{j=1..7} z_j     (Z_0 -> Z_1..Z_7 under the CNOT ring)
//   feat[g,w] = prod_{j=0..w} z_j     (w>=1)
// => gates/f/i/g/o and the whole h_t sequence are input-independent, so
//   out[b,c] = (sum_{t: x[b,t]!=0} s_t[c]) / (cnt_b + 1e-9) + fcb[c]
//   s_t[c]   = sum_h fcW[c,h] * o_h * tanh(c_t[h]),  c_t = f*c_{t-1} + i*g
//
// Single dispatch: every block rebuilds the 128x2 s_t table in LDS (parallel
// across blocks, ~1-2us of VALU, no extra wall time), then pools 4 rows.

__device__ __forceinline__ float sigmoidf_(float v) { return 1.0f / (1.0f + expf(-v)); }

__global__ __launch_bounds__(256) void qlstm_fused(
    const int* __restrict__ x,       // (B,128) int32
    const float* __restrict__ qw,    // (4,2,8)
    const float* __restrict__ Wo,    // (4,256,8)
    const float* __restrict__ bo,    // (4,256)
    const float* __restrict__ fcW,   // (2,256)
    const float* __restrict__ fcb,   // (2,)
    float* __restrict__ out)         // (B,2)
{
  __shared__ float feat[4][8];
  __shared__ float ss[128][2];
  const int tid  = threadIdx.x;
  const int lane = tid & 63;
  const int wv   = tid >> 6;

  // ---- constant per-gate VQC features (threads 0..3) ----
  if (tid < 4) {
    const int g = tid;
    float z[8];
#pragma unroll
    for (int j = 0; j < 8; ++j) z[j] = -sinf(qw[g * 16 + j]);  // qw[g][0][j]
    float p = z[1];
#pragma unroll
    for (int j = 2; j < 8; ++j) p *= z[j];
    feat[g][0] = p;                                 // prod j=1..7
    p = z[0];
#pragma unroll
    for (int w = 1; w < 8; ++w) { p *= z[w]; feat[g][w] = p; }
  }
  __syncthreads();

  // ---- phase A: wave wv builds s_t for t in [32*wv, 32*wv+32) ----
  // lane owns h = lane + 64k, k = 0..3
  float f_[4], S_[4], o_[4], w0_[4], w1_[4];
#pragma unroll
  for (int k = 0; k < 4; ++k) {
    const int h = lane + (k << 6);
    float gate[4];
#pragma unroll
    for (int g = 0; g < 4; ++g) {
      const float* wrow = Wo + ((g << 8) + h) * 8;
      float acc = bo[(g << 8) + h];
#pragma unroll
      for (int q = 0; q < 8; ++q) acc += wrow[q] * feat[g][q];
      gate[g] = acc;
    }
    const float f  = sigmoidf_(gate[0]);
    const float ii = sigmoidf_(gate[1]);
    const float gg = tanhf(gate[2]);
    const float o  = sigmoidf_(gate[3]);
    f_[k] = f; S_[k] = ii * gg; o_[k] = o;
    w0_[k] = fcW[h]; w1_[k] = fcW[256 + h];
  }

  float c_[4] = {0.f, 0.f, 0.f, 0.f};
  const int t_lo = wv << 5, t_hi = t_lo + 32;
  for (int t = 0; t < t_hi; ++t) {
#pragma unroll
    for (int k = 0; k < 4; ++k) c_[k] = f_[k] * c_[k] + S_[k];
    if (t >= t_lo) {
      float q0 = 0.f, q1 = 0.f;
#pragma unroll
      for (int k = 0; k < 4; ++k) {
        const float ht = o_[k] * tanhf(c_[k]);
        q0 += w0_[k] * ht;
        q1 += w1_[k] * ht;
      }
#pragma unroll
      for (int off = 32; off > 0; off >>= 1) {
        q0 += __shfl_down(q0, off);
        q1 += __shfl_down(q1, off);
      }
      if (lane == 0) { ss[t][0] = q0; ss[t][1] = q1; }
    }
  }
  __syncthreads();

  // ---- phase B: pool 4 batch rows (one per wave) ----
  const int b = (blockIdx.x << 2) + wv;
  const int* xb = x + b * 128;
  const int t0 = lane, t1 = lane + 64;
  const int m0 = (xb[t0] != 0) ? 1 : 0;   // lanes read 64 consecutive ints
  const int m1 = (xb[t1] != 0) ? 1 : 0;
  float cnt = (float)(m0 + m1);
  float a0 = 0.f, a1 = 0.f;
  if (m0) { a0 += ss[t0][0]; a1 += ss[t0][1]; }
  if (m1) { a0 += ss[t1][0]; a1 += ss[t1][1]; }

#pragma unroll
  for (int off = 32; off > 0; off >>= 1) {
    cnt += __shfl_down(cnt, off);
    a0  += __shfl_down(a0, off);
    a1  += __shfl_down(a1, off);
  }
  if (lane == 0) {
    const float inv = 1.0f / (cnt + 1e-9f);
    out[b * 2 + 0] = a0 * inv + fcb[0];
    out[b * 2 + 1] = a1 * inv + fcb[1];
  }
}

extern "C" void kernel_launch(void* const* d_in, const int* in_sizes, int n_in,
                              void* d_out, int out_size, void* d_ws, size_t ws_size,
                              hipStream_t stream) {
  // setup_inputs order: x, embed, Wi, bi, qw, Wo, bo, fcW, fcb
  const int*   x   = (const int*)  d_in[0];
  const float* qw  = (const float*)d_in[4];
  const float* Wo  = (const float*)d_in[5];
  const float* bo  = (const float*)d_in[6];
  const float* fcW = (const float*)d_in[7];
  const float* fcb = (const float*)d_in[8];
  float* out = (float*)d_out;

  const int T = 128;
  const int B = in_sizes[0] / T;  // 1024

  qlstm_fused<<<B / 4, 256, 0, stream>>>(x, qw, Wo, bo, fcW, fcb, out);
}